// Round 8
// baseline (77.318 us; speedup 1.0000x reference)
//
#include <hip/hip_runtime.h>
#include <hip/hip_bf16.h>

typedef __bf16 bf16x8 __attribute__((ext_vector_type(8)));
typedef float f32x4 __attribute__((ext_vector_type(4)));
typedef unsigned short ushort8 __attribute__((ext_vector_type(8)));
typedef unsigned short ushort4v __attribute__((ext_vector_type(4)));

constexpr int M = 128;             // B*T
constexpr int K = 4096;            // IN
constexpr int N = 11008;           // OUT
constexpr int BN = 128;            // N cols per block
constexpr int BK = 32;             // K per step
constexpr int KSPLIT = 8;
constexpr long long NW = (long long)N * K;
constexpr int RBLK = 2048;         // reduce blocks

// ws layout
constexpr size_t PART_OFF = 0;                               // 2048 f32 partials
constexpr size_t XBF_OFF  = 8192;                            // X as bf16 (1 MB)
constexpr size_t P_OFF    = XBF_OFF + (size_t)M * K * 2;
constexpr size_t MN       = (size_t)M * N;
constexpr size_t WS_NEED  = P_OFF + KSPLIT * MN * sizeof(float);

__device__ __forceinline__ unsigned short f2bf_bits(float f) {
    unsigned int u = __builtin_bit_cast(unsigned int, f);
    u += 0x7FFFu + ((u >> 16) & 1u);            // RNE to bf16
    return (unsigned short)(u >> 16);
}

// ---- pass 1: per-block partial sum of |W| (no atomics) + X->bf16 convert ----
template <bool CVT>
__global__ __launch_bounds__(256) void absmean_partial(const float* __restrict__ w,
                                                       const float* __restrict__ x,
                                                       float* __restrict__ partials,
                                                       unsigned short* __restrict__ xbf)
{
    const int gtid = blockIdx.x * blockDim.x + threadIdx.x;
    if (CVT && gtid < M * K / 8) {
        const float4* xp = (const float4*)x + (size_t)gtid * 2;
        float4 a = xp[0], b = xp[1];
        ushort8 o;
        o[0] = f2bf_bits(a.x); o[1] = f2bf_bits(a.y);
        o[2] = f2bf_bits(a.z); o[3] = f2bf_bits(a.w);
        o[4] = f2bf_bits(b.x); o[5] = f2bf_bits(b.y);
        o[6] = f2bf_bits(b.z); o[7] = f2bf_bits(b.w);
        *(ushort8*)(xbf + (size_t)gtid * 8) = o;
    }
    const int n4 = (int)(NW / 4);
    const float4* w4 = (const float4*)w;
    float s0 = 0.f, s1 = 0.f, s2 = 0.f, s3 = 0.f;
    for (int i = gtid; i < n4; i += gridDim.x * blockDim.x) {
        float4 v = w4[i];
        s0 += fabsf(v.x); s1 += fabsf(v.y); s2 += fabsf(v.z); s3 += fabsf(v.w);
    }
    float s = (s0 + s1) + (s2 + s3);
#pragma unroll
    for (int off = 32; off > 0; off >>= 1) s += __shfl_down(s, off, 64);
    __shared__ float red[4];
    if ((threadIdx.x & 63) == 0) red[threadIdx.x >> 6] = s;
    __syncthreads();
    if (threadIdx.x == 0)
        partials[blockIdx.x] = (red[0] + red[1]) + (red[2] + red[3]);
}

// ---- pass 2: fused quantize + GEMM, 128x128 tile, wave 64x64 ----
// PRE:  grid(86, KSPLIT), KSTEPS=16, X pre-cvt bf16, partial out (no bias)
// !PRE: grid(86, 1),      KSTEPS=128, inline cvt, direct out + bias
template <int KSTEPS, bool PRE>
__global__ __launch_bounds__(256, 3) void bitlinear_gemm(
    const void* __restrict__ Xsrc, const float* __restrict__ W,
    const float* __restrict__ bias, const float* __restrict__ partials,
    float* __restrict__ dbase)
{
    constexpr int LDSW = 40;                    // 32 + 8 pad shorts (80 B rows)
    __shared__ __attribute__((aligned(16))) unsigned short xs[2][M * LDSW];
    __shared__ __attribute__((aligned(16))) unsigned short wsm[2][BN * LDSW];

    const int tid = threadIdx.x;
    const int lane = tid & 63;
    const int wid = tid >> 6;
    const int wm = wid >> 1;                    // 0..1: M 64-half
    const int wn = wid & 1;                     // 0..1: N 64-half
    const int cgrp = lane >> 4;                 // 0..3
    const int l15 = lane & 15;
    const int n0 = blockIdx.x * BN;
    const int kk0 = PRE ? blockIdx.y * (K / KSPLIT) : 0;
    const int K4 = K / 4;

    const unsigned short* xb = (const unsigned short*)Xsrc;
    const float4* xf = (const float4*)Xsrc;
    const float4* w4p = (const float4*)W;

    ushort8 xr[2];                              // X stage: 2 x 16B per thread
    float4 wr[4];                               // W stage: 4 x 16B per thread

    auto issue = [&](int t) {
#pragma unroll
        for (int i = 0; i < 2; ++i) {           // 512 slots: row=j>>2, chunk=j&3
            const int j = tid + i * 256;
            const int row = j >> 2, ch = j & 3;
            if (PRE) {
                xr[i] = *(const ushort8*)(xb + (size_t)row * K + kk0 + t * BK + ch * 8);
            } else {
                const float4* xp = xf + (size_t)row * K4 + t * (BK / 4) + ch * 2;
                float4 a = xp[0], b = xp[1];
                ushort8 o;
                o[0] = f2bf_bits(a.x); o[1] = f2bf_bits(a.y);
                o[2] = f2bf_bits(a.z); o[3] = f2bf_bits(a.w);
                o[4] = f2bf_bits(b.x); o[5] = f2bf_bits(b.y);
                o[6] = f2bf_bits(b.z); o[7] = f2bf_bits(b.w);
                xr[i] = o;
            }
        }
#pragma unroll
        for (int i = 0; i < 4; ++i) {           // 1024 slots: row=j>>3, q4=j&7
            const int j = tid + i * 256;
            const int row = j >> 3, q = j & 7;
            wr[i] = w4p[(size_t)(n0 + row) * K4 + kk0 / 4 + t * (BK / 4) + q];
        }
    };

    // prologue: tile-0 loads in flight over the delta reduce
    issue(0);

    float s = 0.f;
#pragma unroll
    for (int i = 0; i < RBLK / 256; ++i) s += partials[tid + i * 256];
#pragma unroll
    for (int off = 32; off > 0; off >>= 1) s += __shfl_down(s, off, 64);
    __shared__ float red[4];
    if (lane == 0) red[wid] = s;
    __syncthreads();
    const float delta =
        (float)((double)((red[0] + red[1]) + (red[2] + red[3])) / (double)NW + 1e-8);
    const float inv_delta = 1.0f / delta;

    auto stage = [&](int buf) {
#pragma unroll
        for (int i = 0; i < 2; ++i) {
            const int j = tid + i * 256;
            *(ushort8*)&xs[buf][(j >> 2) * LDSW + (j & 3) * 8] = xr[i];
        }
#pragma unroll
        for (int i = 0; i < 4; ++i) {
            const int j = tid + i * 256;
            const int row = j >> 3, q = j & 7;
            float wf[4] = {wr[i].x, wr[i].y, wr[i].z, wr[i].w};
            ushort4v wq;
#pragma unroll
            for (int e = 0; e < 4; ++e) {
                float qv = rintf(wf[e] * inv_delta);       // RNE = jnp.round
                qv = fminf(1.f, fmaxf(-1.f, qv));
                wq[e] = f2bf_bits(qv);                     // exact bf16 {-1,0,+1}
            }
            *(ushort4v*)&wsm[buf][row * LDSW + q * 4] = wq;
        }
    };

    stage(0);
    __syncthreads();

    f32x4 acc[4][4] = {};

    for (int t = 0; t < KSTEPS; ++t) {
        const int cur = t & 1;
        if (t + 1 < KSTEPS) issue(t + 1);       // globals in flight over MFMA
        const unsigned short* xcur = xs[cur];
        const unsigned short* wcur = wsm[cur];
        bf16x8 afr[4], bfr[4];
#pragma unroll
        for (int f = 0; f < 4; ++f)
            afr[f] = *(const bf16x8*)&xcur[(wm * 64 + f * 16 + l15) * LDSW + cgrp * 8];
#pragma unroll
        for (int g = 0; g < 4; ++g)
            bfr[g] = *(const bf16x8*)&wcur[(wn * 64 + g * 16 + l15) * LDSW + cgrp * 8];
#pragma unroll
        for (int f = 0; f < 4; ++f)
#pragma unroll
            for (int g = 0; g < 4; ++g)
                acc[f][g] = __builtin_amdgcn_mfma_f32_16x16x32_bf16(
                    afr[f], bfr[g], acc[f][g], 0, 0, 0);
        if (t + 1 < KSTEPS) stage(cur ^ 1);
        __syncthreads();
    }

    // epilogue: D col=lane&15, row=(lane>>4)*4+reg (validated)
    float* dst = PRE ? dbase + (size_t)blockIdx.y * MN : dbase;
#pragma unroll
    for (int f = 0; f < 4; ++f) {
        const int mrow = wm * 64 + f * 16 + cgrp * 4;
#pragma unroll
        for (int g = 0; g < 4; ++g) {
            const int ocol = n0 + wn * 64 + g * 16 + l15;
            const float bv = PRE ? 0.f : bias[ocol];
#pragma unroll
            for (int r = 0; r < 4; ++r)
                dst[(size_t)(mrow + r) * N + ocol] = delta * acc[f][g][r] + bv;
        }
    }
}

// ---- pass 3: out = sum_y p_y + bias (fixed index order -> deterministic) ----
__global__ __launch_bounds__(256) void combine(const float* __restrict__ p,
                                               const float* __restrict__ bias,
                                               float4* __restrict__ out)
{
    const int i4 = blockIdx.x * blockDim.x + threadIdx.x;
    constexpr int N4 = N / 4;                   // 2752
    if (i4 >= (int)(MN / 4)) return;
    const int col4 = i4 % N4;
    float4 s = *(const float4*)(bias + col4 * 4);
#pragma unroll
    for (int y = 0; y < KSPLIT; ++y) {
        float4 v = ((const float4*)(p + y * MN))[i4];
        s.x += v.x; s.y += v.y; s.z += v.z; s.w += v.w;
    }
    out[i4] = s;
}

extern "C" void kernel_launch(void* const* d_in, const int* in_sizes, int n_in,
                              void* d_out, int out_size, void* d_ws, size_t ws_size,
                              hipStream_t stream) {
    const float* x = (const float*)d_in[0];
    const float* w = (const float*)d_in[1];
    const float* bias = (const float*)d_in[2];
    float* out = (float*)d_out;
    float* partials = (float*)((char*)d_ws + PART_OFF);
    unsigned short* xbf = (unsigned short*)((char*)d_ws + XBF_OFF);
    float* pbase = (float*)((char*)d_ws + P_OFF);

    if (ws_size >= WS_NEED) {
        absmean_partial<true><<<RBLK, 256, 0, stream>>>(w, x, partials, xbf);
        bitlinear_gemm<K / KSPLIT / BK, true><<<dim3(N / BN, KSPLIT), 256, 0, stream>>>(
            xbf, w, bias, partials, pbase);
        combine<<<(int)(MN / 4 + 255) / 256, 256, 0, stream>>>(pbase, bias, (float4*)out);
    } else {
        absmean_partial<false><<<RBLK, 256, 0, stream>>>(w, x, partials, xbf);
        bitlinear_gemm<K / BK, false><<<dim3(N / BN, 1), 256, 0, stream>>>(
            x, w, bias, partials, out);
    }
}